// Round 4
// baseline (164.627 us; speedup 1.0000x reference)
//
#include <hip/hip_runtime.h>
#include <math.h>

#define Bb 2
#define Ss 128
#define Hh 768
#define Cc 5
#define Mm 256       // Bb*Ss
#define NEGV -1024.0f
#define SCALE 2.8853900817779268f   // 2/ln(2): Ep*Ea = e^{2x}

// haTb: bf16 [b][c][h8][a][h&7], h8=h>>3 in [0,96)   -- stores Ea = exp2(scaled ha)
#define PT 2
#define NBLK (Mm / PT * Cc)   // 640

typedef __attribute__((ext_vector_type(8))) short bf16x8;
typedef __attribute__((ext_vector_type(4))) float f32x4;
typedef unsigned short ushort;

__device__ __forceinline__ unsigned pack_hi16(float hi, float lo) {
    return (__float_as_uint(hi) & 0xFFFF0000u) | (__float_as_uint(lo) >> 16);
}
__device__ __forceinline__ bf16x8 pack_bf16x8(float4 lo, float4 hi) {
    union { bf16x8 v; unsigned u[4]; } r;
    r.u[0] = pack_hi16(lo.y, lo.x);
    r.u[1] = pack_hi16(lo.w, lo.z);
    r.u[2] = pack_hi16(hi.y, hi.x);
    r.u[3] = pack_hi16(hi.w, hi.z);
    return r.v;
}
// round-to-nearest-even bf16 of f32
__device__ __forceinline__ ushort bf16_rne(float f) {
    unsigned b = __float_as_uint(f);
    return (ushort)((b + 0x7FFFu + ((b >> 16) & 1u)) >> 16);
}

#define SB __builtin_amdgcn_sched_barrier(0);

// ---------------- Kernel 1: LDS-staged bf16 MFMA GEMM ----------------
// hp branch stores Ep=exp2(hp') fp32; ha branch stores Ea=exp2(ha') bf16.
// K-loop unrolled x2 with double register staging (loads 2 sub-iters ahead).

#define GEMM_STEP(PA0, PA1, PB0, PB1, KNEXT) \
    *(bf16x8*)&Asb[srow][sko] = pack_bf16x8(PA0, PA1); \
    if (tid < 128) *(bf16x8*)&Bsb[tid >> 2][sko] = pack_bf16x8(PB0, PB1); \
    __syncthreads(); \
    if ((KNEXT) < Hh) { \
        PA0 = *(const float4*)(gA + (KNEXT)); \
        PA1 = *(const float4*)(gA + (KNEXT) + 4); \
        if (tid < 128) { \
            PB0 = *(const float4*)(gB + (KNEXT)); \
            PB1 = *(const float4*)(gB + (KNEXT) + 4); \
        } \
    } \
    { \
        bf16x8 af = *(const bf16x8*)&Asb[wave * 16 + l16][quad * 8]; \
        bf16x8 b0 = *(const bf16x8*)&Bsb[l16][quad * 8]; \
        bf16x8 b1 = *(const bf16x8*)&Bsb[16 + l16][quad * 8]; \
        acc0 = __builtin_amdgcn_mfma_f32_16x16x32_bf16(af, b0, acc0, 0, 0, 0); \
        acc1 = __builtin_amdgcn_mfma_f32_16x16x32_bf16(af, b1, acc1, 0, 0, 0); \
    } \
    __syncthreads();

__global__ __launch_bounds__(256)
void gemm_mfma(const float* __restrict__ X,
               const float* __restrict__ Wprd,
               const float* __restrict__ Warg,
               const float* __restrict__ bprd,
               const float* __restrict__ barg,
               float* __restrict__ EpG,
               ushort* __restrict__ haTb,
               float* __restrict__ accum)
{
    __shared__ __align__(16) ushort Asb[64][40];
    __shared__ __align__(16) ushort Bsb[32][40];

    if (blockIdx.x == 0 && blockIdx.y == 0 && threadIdx.x == 0) {
        accum[0] = 0.f; accum[1] = 0.f;
        ((unsigned*)accum)[2] = 0u;      // completion counter
    }
    const int bm   = blockIdx.x;          // 0..3   (64 rows)
    const int bn   = blockIdx.y;          // 0..143 (32 cols)
    const int tid  = threadIdx.x;
    const int wave = tid >> 6;
    const int lane = tid & 63;
    const int l16  = lane & 15;
    const int quad = lane >> 4;

    const float* Wsrc; const float* bsrc;
    const int nb = bn * 32;
    if (nb < Hh) { Wsrc = Wprd + (size_t)nb * Hh;        bsrc = bprd + nb; }
    else         { Wsrc = Warg + (size_t)(nb - Hh) * Hh; bsrc = barg + (nb - Hh); }

    const int srow = tid >> 2;
    const int sko  = (tid & 3) * 8;
    const float* gA = X + (size_t)(bm * 64 + srow) * Hh + sko;
    const float* gB = Wsrc + (size_t)(tid >> 2) * Hh + sko;   // valid for tid<128

    // stage0: k=0 ; stage1: k=32
    float4 a00 = *(const float4*)(gA);
    float4 a01 = *(const float4*)(gA + 4);
    float4 a10 = *(const float4*)(gA + 32);
    float4 a11 = *(const float4*)(gA + 36);
    float4 b00, b01, b10, b11;
    if (tid < 128) {
        b00 = *(const float4*)(gB);      b01 = *(const float4*)(gB + 4);
        b10 = *(const float4*)(gB + 32); b11 = *(const float4*)(gB + 36);
    }

    f32x4 acc0 = {0.f,0.f,0.f,0.f}, acc1 = {0.f,0.f,0.f,0.f};

    for (int k0 = 0; k0 < Hh; k0 += 64) {
        GEMM_STEP(a00, a01, b00, b01, k0 + 64)    // consumes k0,    prefetch k0+64
        GEMM_STEP(a10, a11, b10, b11, k0 + 96)    // consumes k0+32, prefetch k0+96
    }

    const float sb0 = SCALE * bsrc[l16];
    const float sb1 = SCALE * bsrc[16 + l16];
    const int row = bm * 64 + wave * 16 + quad * 4;

    if (nb < Hh) {   // Ep: row-major fp32 [m][h] = exp2(hp')
        #pragma unroll
        for (int r = 0; r < 4; ++r) {
            const int mm = row + r;
            EpG[(size_t)mm * Hh + nb + l16]      = __builtin_amdgcn_exp2f(SCALE * acc0[r] + sb0);
            EpG[(size_t)mm * Hh + nb + 16 + l16] = __builtin_amdgcn_exp2f(SCALE * acc1[r] + sb1);
        }
    } else {         // Ea = exp2(ha') -> haTb bf16 [b][c][h>>3][a][h&7]
        const int q  = nb - Hh;
        const int cU = q / Hh;
        const int h0 = q % Hh;
        const int hA = h0 + l16;
        const int hB = h0 + 16 + l16;
        const size_t offA = (size_t)(hA >> 3) * 1024 + (hA & 7);
        const size_t offB = (size_t)(hB >> 3) * 1024 + (hB & 7);
        #pragma unroll
        for (int r = 0; r < 4; ++r) {
            const int mm = row + r;
            const int bI = mm >> 7, aI = mm & 127;
            const size_t base = ((size_t)(bI * Cc + cU) * 96) * 1024 + (size_t)aI * 8;
            const float e0 = __builtin_amdgcn_exp2f(SCALE * acc0[r] + sb0);
            const float e1 = __builtin_amdgcn_exp2f(SCALE * acc1[r] + sb1);
            haTb[base + offA] = bf16_rne(e0);
            haTb[base + offB] = bf16_rne(e1);
        }
    }
}

// ---------------- Kernel 2: biaffine ----------------
// Grid 640 = (p-tile, c), 512 thr: tid = hq*128 + a. term = w * rcp(Ep*Ea + 1).
// w/ep0/ep1 staged in LDS (9 KB) and read via broadcast ds_read -- replaces
// the per-C1 scalar-cache (s_load) stream that was thrashing sK$ and serializing
// every consume group on scalar-miss latency.
#define LOADG4(R, g) \
    R##0 = hap4[((g)*4+0)*128]; R##1 = hap4[((g)*4+1)*128]; \
    R##2 = hap4[((g)*4+2)*128]; R##3 = hap4[((g)*4+3)*128];

#define C1(u, hx) { \
    float w8[8], q0[8], q1[8]; \
    _Pragma("unroll") \
    for (int z = 0; z < 8; ++z) { \
        w8[z] = wS[(hx) + z]; q0[z] = e0S[(hx) + z]; q1[z] = e1S[(hx) + z]; \
    } \
    const float e0 = __uint_as_float((u).x << 16); \
    const float e1 = __uint_as_float((u).x & 0xFFFF0000u); \
    const float e2 = __uint_as_float((u).y << 16); \
    const float e3 = __uint_as_float((u).y & 0xFFFF0000u); \
    const float e4 = __uint_as_float((u).z << 16); \
    const float e5 = __uint_as_float((u).z & 0xFFFF0000u); \
    const float e6 = __uint_as_float((u).w << 16); \
    const float e7 = __uint_as_float((u).w & 0xFFFF0000u); \
    float r; \
    r = __builtin_amdgcn_rcpf(fmaf(q0[0], e0, 1.0f)); ac00 = fmaf(w8[0], r, ac00); \
    r = __builtin_amdgcn_rcpf(fmaf(q0[1], e1, 1.0f)); ac01 = fmaf(w8[1], r, ac01); \
    r = __builtin_amdgcn_rcpf(fmaf(q0[2], e2, 1.0f)); ac00 = fmaf(w8[2], r, ac00); \
    r = __builtin_amdgcn_rcpf(fmaf(q0[3], e3, 1.0f)); ac01 = fmaf(w8[3], r, ac01); \
    r = __builtin_amdgcn_rcpf(fmaf(q0[4], e4, 1.0f)); ac00 = fmaf(w8[4], r, ac00); \
    r = __builtin_amdgcn_rcpf(fmaf(q0[5], e5, 1.0f)); ac01 = fmaf(w8[5], r, ac01); \
    r = __builtin_amdgcn_rcpf(fmaf(q0[6], e6, 1.0f)); ac00 = fmaf(w8[6], r, ac00); \
    r = __builtin_amdgcn_rcpf(fmaf(q0[7], e7, 1.0f)); ac01 = fmaf(w8[7], r, ac01); \
    r = __builtin_amdgcn_rcpf(fmaf(q1[0], e0, 1.0f)); ac10 = fmaf(w8[0], r, ac10); \
    r = __builtin_amdgcn_rcpf(fmaf(q1[1], e1, 1.0f)); ac11 = fmaf(w8[1], r, ac11); \
    r = __builtin_amdgcn_rcpf(fmaf(q1[2], e2, 1.0f)); ac10 = fmaf(w8[2], r, ac10); \
    r = __builtin_amdgcn_rcpf(fmaf(q1[3], e3, 1.0f)); ac11 = fmaf(w8[3], r, ac11); \
    r = __builtin_amdgcn_rcpf(fmaf(q1[4], e4, 1.0f)); ac10 = fmaf(w8[4], r, ac10); \
    r = __builtin_amdgcn_rcpf(fmaf(q1[5], e5, 1.0f)); ac11 = fmaf(w8[5], r, ac11); \
    r = __builtin_amdgcn_rcpf(fmaf(q1[6], e6, 1.0f)); ac10 = fmaf(w8[6], r, ac10); \
    r = __builtin_amdgcn_rcpf(fmaf(q1[7], e7, 1.0f)); ac11 = fmaf(w8[7], r, ac11); \
}

#define CONSUMEG4(R, g) \
    C1(R##0, hbase + ((g)*4+0)*8)  C1(R##1, hbase + ((g)*4+1)*8) \
    C1(R##2, hbase + ((g)*4+2)*8)  C1(R##3, hbase + ((g)*4+3)*8)

__global__ __launch_bounds__(512, 6)
void biaffine_loss(const float* __restrict__ EpG,
                   const ushort* __restrict__ haTb,
                   const float* __restrict__ Wout,
                   const int* __restrict__ ng,
                   const int* __restrict__ att,
                   const float* __restrict__ target,
                   float* __restrict__ out_logits,
                   float* __restrict__ accum,
                   float* __restrict__ out_loss)
{
    __shared__ float partial[PT][3][Ss];
    __shared__ float maskneg[PT][Ss];
    __shared__ float redmax[PT][2];
    __shared__ float red3[PT][2][3];
    __shared__ float swr_s;
    __shared__ __align__(16) float wS[Hh];
    __shared__ __align__(16) float e0S[Hh];
    __shared__ __align__(16) float e1S[Hh];

    // XCD-chunked bijective swizzle (NBLK=640, 8 XCDs, 80 blocks/XCD):
    // physical p -> logical L = (p%8)*80 + p/8; logical order is slab-major:
    // g = L/64 = b*Cc + c (one Ea slab), j = L%64 -> pt = b*64 + j.
    const int L   = ((int)blockIdx.x & 7) * 80 + ((int)blockIdx.x >> 3);
    const int g   = L >> 6;              // 0..9
    const int j   = L & 63;
    const int b   = (g >= Cc) ? 1 : 0;
    const int c   = g - b * Cc;
    const int bp0 = (b * 64 + j) * PT;
    const int tid = threadIdx.x;
    const int a   = tid & (Ss - 1);
    const int hq  = __builtin_amdgcn_readfirstlane(tid >> 7);   // 0..3, forced SGPR
    const int lane = tid & 63;

    const float* wrow = Wout + (size_t)c * Hh;
    const float* ep0  = EpG + (size_t)(bp0 + 0) * Hh;
    const float* ep1  = EpG + (size_t)(bp0 + 1) * Hh;

    if (tid < PT * Ss) {   // mask staging: unconditional ng loads (no att->ng chain)
        const int p_i = tid >> 7;
        const int aa  = tid & (Ss - 1);
        const int attv = att[b * Ss + aa];
        const int* ngp = ng + (size_t)(bp0 + p_i) * Cc * Ss + aa;
        const int n0 = ngp[0 * Ss], n1 = ngp[1 * Ss], n2 = ngp[2 * Ss],
                  n3 = ngp[3 * Ss], n4 = ngp[4 * Ss];
        const int any = (n0 | n1 | n2 | n3 | n4) & (attv > 0 ? -1 : 0);
        maskneg[p_i][aa] = any ? 0.0f : NEGV;
    }

    if (tid < 64) {    // wave 0: sumW[c] from global (coalesced)
        float s = 0.f;
        #pragma unroll
        for (int i = 0; i < Hh / 64; ++i) s += wrow[tid + i * 64];
        #pragma unroll
        for (int off = 32; off; off >>= 1) s += __shfl_xor(s, off, 64);
        if (tid == 0) swr_s = s;
    }

    // stage w / ep rows into LDS (coalesced, 9 KB total)
    for (int i = tid; i < Hh; i += 512) {
        wS[i]  = wrow[i];
        e0S[i] = ep0[i];
        e1S[i] = ep1[i];
    }

    // thread's Ea stream: uint4 j (8 h each); index = (hq*24 + j)*128 + a
    const uint4* hap4 = (const uint4*)(haTb + ((size_t)(b * Cc + c) * 96) * 1024)
                      + (size_t)hq * 24 * 128 + a;
    const int hbase = hq * 192;

    uint4 A0, A1, A2, A3;
    uint4 B0, B1, B2, B3;
    float ac00 = 0.f, ac01 = 0.f, ac10 = 0.f, ac11 = 0.f;

    LOADG4(A, 0)
    __syncthreads();       // LDS w/ep ready; global A-group already in flight
    SB
    LOADG4(B, 1) SB  CONSUMEG4(A, 0) SB
    LOADG4(A, 2) SB  CONSUMEG4(B, 1) SB
    LOADG4(B, 3) SB  CONSUMEG4(A, 2) SB
    LOADG4(A, 4) SB  CONSUMEG4(B, 3) SB
    LOADG4(B, 5) SB  CONSUMEG4(A, 4) SB
    CONSUMEG4(B, 5)

    if (hq != 0) {
        partial[0][hq - 1][a] = ac00 + ac01;
        partial[1][hq - 1][a] = ac10 + ac11;
    }
    __syncthreads();

    float logit[PT];
    const int wv = tid >> 6;             // 0/1 for hq==0 threads
    if (hq == 0) {
        const float ps[PT] = { ac00 + ac01, ac10 + ac11 };
        #pragma unroll
        for (int p = 0; p < PT; ++p) {
            const float full = ps[p] + partial[p][0][a] + partial[p][1][a] + partial[p][2][a];
            logit[p] = swr_s - 2.0f * full + maskneg[p][a];
            out_logits[((size_t)(bp0 + p) * Cc + c) * Ss + a] = logit[p];
            float mx = logit[p];
            #pragma unroll
            for (int off = 32; off; off >>= 1) mx = fmaxf(mx, __shfl_xor(mx, off, 64));
            if (lane == 0) redmax[p][wv] = mx;
        }
    }
    __syncthreads();

    if (hq == 0) {
        #pragma unroll
        for (int p = 0; p < PT; ++p) {
            const float rm = fmaxf(redmax[p][0], redmax[p][1]);
            const float e  = __builtin_amdgcn_exp2f((logit[p] - rm) * 1.4426950408889634f);
            const float tg = target[((size_t)(bp0 + p) * Cc + c) * Ss + a];
            float se = e, st = tg, sx = tg * logit[p];
            #pragma unroll
            for (int off = 32; off; off >>= 1) {
                se += __shfl_xor(se, off, 64);
                st += __shfl_xor(st, off, 64);
                sx += __shfl_xor(sx, off, 64);
            }
            if (lane == 0) { red3[p][wv][0] = se; red3[p][wv][1] = st; red3[p][wv][2] = sx; }
        }
    }
    __syncthreads();

    if (tid == 0) {
        float nsum = 0.f, dsum = 0.f;
        #pragma unroll
        for (int p = 0; p < PT; ++p) {
            const float rm = fmaxf(redmax[p][0], redmax[p][1]);
            const float SE = red3[p][0][0] + red3[p][1][0];
            const float ST = red3[p][0][1] + red3[p][1][1];
            const float SX = red3[p][0][2] + red3[p][1][2];
            const float lse = rm + __builtin_amdgcn_logf(SE) * 0.6931471805599453f;
            nsum += lse * ST - SX;
            dsum += ST;
        }
        atomicAdd(&accum[0], nsum);
        atomicAdd(&accum[1], dsum);
        __threadfence();
        const unsigned old = atomicAdd((unsigned*)(accum + 2), 1u);
        if (old == (unsigned)(NBLK - 1)) {          // last block: finalize loss
            const float n = atomicAdd(&accum[0], 0.0f);
            const float d = atomicAdd(&accum[1], 0.0f);
            out_loss[0] = n / d;
        }
    }
}

extern "C" void kernel_launch(void* const* d_in, const int* in_sizes, int n_in,
                              void* d_out, int out_size, void* d_ws, size_t ws_size,
                              hipStream_t stream) {
    const float* seq    = (const float*)d_in[0];
    const int*   att    = (const int*)  d_in[1];
    const int*   ng     = (const int*)  d_in[2];
    const float* target = (const float*)d_in[3];
    const float* Wprd   = (const float*)d_in[4];
    const float* bprd   = (const float*)d_in[5];
    const float* Warg   = (const float*)d_in[6];
    const float* barg   = (const float*)d_in[7];
    const float* Wout   = (const float*)d_in[8];

    float*  out    = (float*)d_out;
    float*  EpG    = (float*)d_ws;                       // 196608 floats
    ushort* haTb   = (ushort*)(EpG + 196608);            // 983040 ushorts
    float*  accum  = EpG + 196608 + 491520;              // 3 slots

    gemm_mfma<<<dim3(4, 144), 256, 0, stream>>>(seq, Wprd, Warg, bprd, barg,
                                                EpG, haTb, accum);
    biaffine_loss<<<dim3(NBLK), 512, 0, stream>>>(EpG, haTb, Wout, ng, att, target,
                                                  out + 1, accum, out);
}

// Round 5
// 127.826 us; speedup vs baseline: 1.2879x; 1.2879x over previous
//
#include <hip/hip_runtime.h>
#include <math.h>

#define Bb 2
#define Ss 128
#define Hh 768
#define Cc 5
#define Mm 256       // Bb*Ss
#define NEGV -1024.0f
#define SCALE 2.8853900817779268f   // 2/ln(2): Ep*Ea = e^{2x}

// haTb: bf16 [b][c][h8][a][h&7], h8=h>>3 in [0,96)   -- stores Ea = exp2(scaled ha)
#define PT 2
#define NBLK (Mm / PT * Cc)   // 640

typedef __attribute__((ext_vector_type(8))) short bf16x8;
typedef __attribute__((ext_vector_type(4))) float f32x4;
typedef unsigned short ushort;

__device__ __forceinline__ unsigned pack_hi16(float hi, float lo) {
    return (__float_as_uint(hi) & 0xFFFF0000u) | (__float_as_uint(lo) >> 16);
}
__device__ __forceinline__ bf16x8 pack_bf16x8(float4 lo, float4 hi) {
    union { bf16x8 v; unsigned u[4]; } r;
    r.u[0] = pack_hi16(lo.y, lo.x);
    r.u[1] = pack_hi16(lo.w, lo.z);
    r.u[2] = pack_hi16(hi.y, hi.x);
    r.u[3] = pack_hi16(hi.w, hi.z);
    return r.v;
}
// round-to-nearest-even bf16 of f32
__device__ __forceinline__ ushort bf16_rne(float f) {
    unsigned b = __float_as_uint(f);
    return (ushort)((b + 0x7FFFu + ((b >> 16) & 1u)) >> 16);
}

#define SB __builtin_amdgcn_sched_barrier(0);

// ---------------- Kernel 1: LDS-staged bf16 MFMA GEMM ----------------
// hp branch stores Ep=exp2(hp') fp32; ha branch stores Ea=exp2(ha') bf16.
// K-loop unrolled x2 with double register staging (loads 2 sub-iters ahead).

#define GEMM_STEP(PA0, PA1, PB0, PB1, KNEXT) \
    *(bf16x8*)&Asb[srow][sko] = pack_bf16x8(PA0, PA1); \
    if (tid < 128) *(bf16x8*)&Bsb[tid >> 2][sko] = pack_bf16x8(PB0, PB1); \
    __syncthreads(); \
    if ((KNEXT) < Hh) { \
        PA0 = *(const float4*)(gA + (KNEXT)); \
        PA1 = *(const float4*)(gA + (KNEXT) + 4); \
        if (tid < 128) { \
            PB0 = *(const float4*)(gB + (KNEXT)); \
            PB1 = *(const float4*)(gB + (KNEXT) + 4); \
        } \
    } \
    { \
        bf16x8 af = *(const bf16x8*)&Asb[wave * 16 + l16][quad * 8]; \
        bf16x8 b0 = *(const bf16x8*)&Bsb[l16][quad * 8]; \
        bf16x8 b1 = *(const bf16x8*)&Bsb[16 + l16][quad * 8]; \
        acc0 = __builtin_amdgcn_mfma_f32_16x16x32_bf16(af, b0, acc0, 0, 0, 0); \
        acc1 = __builtin_amdgcn_mfma_f32_16x16x32_bf16(af, b1, acc1, 0, 0, 0); \
    } \
    __syncthreads();

__global__ __launch_bounds__(256)
void gemm_mfma(const float* __restrict__ X,
               const float* __restrict__ Wprd,
               const float* __restrict__ Warg,
               const float* __restrict__ bprd,
               const float* __restrict__ barg,
               float* __restrict__ EpG,
               ushort* __restrict__ haTb,
               float* __restrict__ accum)
{
    __shared__ __align__(16) ushort Asb[64][40];
    __shared__ __align__(16) ushort Bsb[32][40];

    if (blockIdx.x == 0 && blockIdx.y == 0 && threadIdx.x == 0) {
        accum[0] = 0.f; accum[1] = 0.f;
        ((unsigned*)accum)[2] = 0u;      // completion counter
    }
    const int bm   = blockIdx.x;          // 0..3   (64 rows)
    const int bn   = blockIdx.y;          // 0..143 (32 cols)
    const int tid  = threadIdx.x;
    const int wave = tid >> 6;
    const int lane = tid & 63;
    const int l16  = lane & 15;
    const int quad = lane >> 4;

    const float* Wsrc; const float* bsrc;
    const int nb = bn * 32;
    if (nb < Hh) { Wsrc = Wprd + (size_t)nb * Hh;        bsrc = bprd + nb; }
    else         { Wsrc = Warg + (size_t)(nb - Hh) * Hh; bsrc = barg + (nb - Hh); }

    const int srow = tid >> 2;
    const int sko  = (tid & 3) * 8;
    const float* gA = X + (size_t)(bm * 64 + srow) * Hh + sko;
    const float* gB = Wsrc + (size_t)(tid >> 2) * Hh + sko;   // valid for tid<128

    // stage0: k=0 ; stage1: k=32
    float4 a00 = *(const float4*)(gA);
    float4 a01 = *(const float4*)(gA + 4);
    float4 a10 = *(const float4*)(gA + 32);
    float4 a11 = *(const float4*)(gA + 36);
    float4 b00, b01, b10, b11;
    if (tid < 128) {
        b00 = *(const float4*)(gB);      b01 = *(const float4*)(gB + 4);
        b10 = *(const float4*)(gB + 32); b11 = *(const float4*)(gB + 36);
    }

    f32x4 acc0 = {0.f,0.f,0.f,0.f}, acc1 = {0.f,0.f,0.f,0.f};

    for (int k0 = 0; k0 < Hh; k0 += 64) {
        GEMM_STEP(a00, a01, b00, b01, k0 + 64)    // consumes k0,    prefetch k0+64
        GEMM_STEP(a10, a11, b10, b11, k0 + 96)    // consumes k0+32, prefetch k0+96
    }

    const float sb0 = SCALE * bsrc[l16];
    const float sb1 = SCALE * bsrc[16 + l16];
    const int row = bm * 64 + wave * 16 + quad * 4;

    if (nb < Hh) {   // Ep: row-major fp32 [m][h] = exp2(hp')
        #pragma unroll
        for (int r = 0; r < 4; ++r) {
            const int mm = row + r;
            EpG[(size_t)mm * Hh + nb + l16]      = __builtin_amdgcn_exp2f(SCALE * acc0[r] + sb0);
            EpG[(size_t)mm * Hh + nb + 16 + l16] = __builtin_amdgcn_exp2f(SCALE * acc1[r] + sb1);
        }
    } else {         // Ea = exp2(ha') -> haTb bf16 [b][c][h>>3][a][h&7]
        const int q  = nb - Hh;
        const int cU = q / Hh;
        const int h0 = q % Hh;
        const int hA = h0 + l16;
        const int hB = h0 + 16 + l16;
        const size_t offA = (size_t)(hA >> 3) * 1024 + (hA & 7);
        const size_t offB = (size_t)(hB >> 3) * 1024 + (hB & 7);
        #pragma unroll
        for (int r = 0; r < 4; ++r) {
            const int mm = row + r;
            const int bI = mm >> 7, aI = mm & 127;
            const size_t base = ((size_t)(bI * Cc + cU) * 96) * 1024 + (size_t)aI * 8;
            const float e0 = __builtin_amdgcn_exp2f(SCALE * acc0[r] + sb0);
            const float e1 = __builtin_amdgcn_exp2f(SCALE * acc1[r] + sb1);
            haTb[base + offA] = bf16_rne(e0);
            haTb[base + offB] = bf16_rne(e1);
        }
    }
}

// ---------------- Kernel 2: biaffine ----------------
// Grid 640 = (p-tile, c), 512 thr: tid = hq*128 + a. term = w * rcp(Ep*Ea + 1).
// w/ep0/ep1 staged in LDS (9 KB) and read via broadcast ds_read.
// Round-4 lesson: the previous LDS attempt spilled (118 MB scratch writes) --
// macro-local float arrays + launch_bounds(512,6) VGPR cap. Fix: no local
// aggregates (inline LDS reads, <=4 temps live) and launch_bounds(512,4).
#define LOADG4(R, g) \
    R##0 = hap4[((g)*4+0)*128]; R##1 = hap4[((g)*4+1)*128]; \
    R##2 = hap4[((g)*4+2)*128]; R##3 = hap4[((g)*4+3)*128];

// one h-term for both p rows; z parity picks the accumulator pair (same
// per-accumulator add order as the R2 kernel -> bit-identical results)
#define PAIR(z, ee) { \
    const float ww = wS[hx + (z)]; \
    const float r0 = __builtin_amdgcn_rcpf(fmaf(e0S[hx + (z)], (ee), 1.0f)); \
    const float r1 = __builtin_amdgcn_rcpf(fmaf(e1S[hx + (z)], (ee), 1.0f)); \
    if ((z) & 1) { ac01 = fmaf(ww, r0, ac01); ac11 = fmaf(ww, r1, ac11); } \
    else         { ac00 = fmaf(ww, r0, ac00); ac10 = fmaf(ww, r1, ac10); } \
}

#define C1(u, hx_) { \
    const int hx = (hx_); \
    PAIR(0, __uint_as_float((u).x << 16)) \
    PAIR(1, __uint_as_float((u).x & 0xFFFF0000u)) \
    PAIR(2, __uint_as_float((u).y << 16)) \
    PAIR(3, __uint_as_float((u).y & 0xFFFF0000u)) \
    PAIR(4, __uint_as_float((u).z << 16)) \
    PAIR(5, __uint_as_float((u).z & 0xFFFF0000u)) \
    PAIR(6, __uint_as_float((u).w << 16)) \
    PAIR(7, __uint_as_float((u).w & 0xFFFF0000u)) \
}

#define CONSUMEG4(R, g) \
    C1(R##0, hbase + ((g)*4+0)*8)  C1(R##1, hbase + ((g)*4+1)*8) \
    C1(R##2, hbase + ((g)*4+2)*8)  C1(R##3, hbase + ((g)*4+3)*8)

__global__ __launch_bounds__(512, 4)
void biaffine_loss(const float* __restrict__ EpG,
                   const ushort* __restrict__ haTb,
                   const float* __restrict__ Wout,
                   const int* __restrict__ ng,
                   const int* __restrict__ att,
                   const float* __restrict__ target,
                   float* __restrict__ out_logits,
                   float* __restrict__ accum,
                   float* __restrict__ out_loss)
{
    __shared__ float partial[PT][3][Ss];
    __shared__ float maskneg[PT][Ss];
    __shared__ float redmax[PT][2];
    __shared__ float red3[PT][2][3];
    __shared__ float swr_s;
    __shared__ __align__(16) float wS[Hh];
    __shared__ __align__(16) float e0S[Hh];
    __shared__ __align__(16) float e1S[Hh];

    // XCD-chunked bijective swizzle (NBLK=640, 8 XCDs, 80 blocks/XCD):
    // physical p -> logical L = (p%8)*80 + p/8; logical order is slab-major:
    // g = L/64 = b*Cc + c (one Ea slab), j = L%64 -> pt = b*64 + j.
    const int L   = ((int)blockIdx.x & 7) * 80 + ((int)blockIdx.x >> 3);
    const int g   = L >> 6;              // 0..9
    const int j   = L & 63;
    const int b   = (g >= Cc) ? 1 : 0;
    const int c   = g - b * Cc;
    const int bp0 = (b * 64 + j) * PT;
    const int tid = threadIdx.x;
    const int a   = tid & (Ss - 1);
    const int hq  = __builtin_amdgcn_readfirstlane(tid >> 7);   // 0..3, forced SGPR
    const int lane = tid & 63;

    const float* wrow = Wout + (size_t)c * Hh;
    const float* ep0  = EpG + (size_t)(bp0 + 0) * Hh;
    const float* ep1  = EpG + (size_t)(bp0 + 1) * Hh;

    if (tid < PT * Ss) {   // mask staging: unconditional ng loads (no att->ng chain)
        const int p_i = tid >> 7;
        const int aa  = tid & (Ss - 1);
        const int attv = att[b * Ss + aa];
        const int* ngp = ng + (size_t)(bp0 + p_i) * Cc * Ss + aa;
        const int n0 = ngp[0 * Ss], n1 = ngp[1 * Ss], n2 = ngp[2 * Ss],
                  n3 = ngp[3 * Ss], n4 = ngp[4 * Ss];
        const int any = (n0 | n1 | n2 | n3 | n4) & (attv > 0 ? -1 : 0);
        maskneg[p_i][aa] = any ? 0.0f : NEGV;
    }

    if (tid < 64) {    // wave 0: sumW[c] from global (coalesced)
        float s = 0.f;
        #pragma unroll
        for (int i = 0; i < Hh / 64; ++i) s += wrow[tid + i * 64];
        #pragma unroll
        for (int off = 32; off; off >>= 1) s += __shfl_xor(s, off, 64);
        if (tid == 0) swr_s = s;
    }

    // stage w / ep rows into LDS (coalesced, 9 KB total)
    for (int i = tid; i < Hh; i += 512) {
        wS[i]  = wrow[i];
        e0S[i] = ep0[i];
        e1S[i] = ep1[i];
    }

    // thread's Ea stream: uint4 j (8 h each); index = (hq*24 + j)*128 + a
    const uint4* hap4 = (const uint4*)(haTb + ((size_t)(b * Cc + c) * 96) * 1024)
                      + (size_t)hq * 24 * 128 + a;
    const int hbase = hq * 192;

    uint4 A0, A1, A2, A3;
    uint4 B0, B1, B2, B3;
    float ac00 = 0.f, ac01 = 0.f, ac10 = 0.f, ac11 = 0.f;

    LOADG4(A, 0)
    __syncthreads();       // LDS w/ep ready; global A-group already in flight
    SB
    LOADG4(B, 1) SB  CONSUMEG4(A, 0) SB
    LOADG4(A, 2) SB  CONSUMEG4(B, 1) SB
    LOADG4(B, 3) SB  CONSUMEG4(A, 2) SB
    LOADG4(A, 4) SB  CONSUMEG4(B, 3) SB
    LOADG4(B, 5) SB  CONSUMEG4(A, 4) SB
    CONSUMEG4(B, 5)

    if (hq != 0) {
        partial[0][hq - 1][a] = ac00 + ac01;
        partial[1][hq - 1][a] = ac10 + ac11;
    }
    __syncthreads();

    float logit[PT];
    const int wv = tid >> 6;             // 0/1 for hq==0 threads
    if (hq == 0) {
        const float ps[PT] = { ac00 + ac01, ac10 + ac11 };
        #pragma unroll
        for (int p = 0; p < PT; ++p) {
            const float full = ps[p] + partial[p][0][a] + partial[p][1][a] + partial[p][2][a];
            logit[p] = swr_s - 2.0f * full + maskneg[p][a];
            out_logits[((size_t)(bp0 + p) * Cc + c) * Ss + a] = logit[p];
            float mx = logit[p];
            #pragma unroll
            for (int off = 32; off; off >>= 1) mx = fmaxf(mx, __shfl_xor(mx, off, 64));
            if (lane == 0) redmax[p][wv] = mx;
        }
    }
    __syncthreads();

    if (hq == 0) {
        #pragma unroll
        for (int p = 0; p < PT; ++p) {
            const float rm = fmaxf(redmax[p][0], redmax[p][1]);
            const float e  = __builtin_amdgcn_exp2f((logit[p] - rm) * 1.4426950408889634f);
            const float tg = target[((size_t)(bp0 + p) * Cc + c) * Ss + a];
            float se = e, st = tg, sx = tg * logit[p];
            #pragma unroll
            for (int off = 32; off; off >>= 1) {
                se += __shfl_xor(se, off, 64);
                st += __shfl_xor(st, off, 64);
                sx += __shfl_xor(sx, off, 64);
            }
            if (lane == 0) { red3[p][wv][0] = se; red3[p][wv][1] = st; red3[p][wv][2] = sx; }
        }
    }
    __syncthreads();

    if (tid == 0) {
        float nsum = 0.f, dsum = 0.f;
        #pragma unroll
        for (int p = 0; p < PT; ++p) {
            const float rm = fmaxf(redmax[p][0], redmax[p][1]);
            const float SE = red3[p][0][0] + red3[p][1][0];
            const float ST = red3[p][0][1] + red3[p][1][1];
            const float SX = red3[p][0][2] + red3[p][1][2];
            const float lse = rm + __builtin_amdgcn_logf(SE) * 0.6931471805599453f;
            nsum += lse * ST - SX;
            dsum += ST;
        }
        atomicAdd(&accum[0], nsum);
        atomicAdd(&accum[1], dsum);
        __threadfence();
        const unsigned old = atomicAdd((unsigned*)(accum + 2), 1u);
        if (old == (unsigned)(NBLK - 1)) {          // last block: finalize loss
            const float n = atomicAdd(&accum[0], 0.0f);
            const float d = atomicAdd(&accum[1], 0.0f);
            out_loss[0] = n / d;
        }
    }
}

extern "C" void kernel_launch(void* const* d_in, const int* in_sizes, int n_in,
                              void* d_out, int out_size, void* d_ws, size_t ws_size,
                              hipStream_t stream) {
    const float* seq    = (const float*)d_in[0];
    const int*   att    = (const int*)  d_in[1];
    const int*   ng     = (const int*)  d_in[2];
    const float* target = (const float*)d_in[3];
    const float* Wprd   = (const float*)d_in[4];
    const float* bprd   = (const float*)d_in[5];
    const float* Warg   = (const float*)d_in[6];
    const float* barg   = (const float*)d_in[7];
    const float* Wout   = (const float*)d_in[8];

    float*  out    = (float*)d_out;
    float*  EpG    = (float*)d_ws;                       // 196608 floats
    ushort* haTb   = (ushort*)(EpG + 196608);            // 983040 ushorts
    float*  accum  = EpG + 196608 + 491520;              // 3 slots

    gemm_mfma<<<dim3(4, 144), 256, 0, stream>>>(seq, Wprd, Warg, bprd, barg,
                                                EpG, haTb, accum);
    biaffine_loss<<<dim3(NBLK), 512, 0, stream>>>(EpG, haTb, Wout, ng, att, target,
                                                  out + 1, accum, out);
}